// Round 11
// baseline (89.882 us; speedup 1.0000x reference)
//
#include <hip/hip_runtime.h>
#include <stdint.h>

// Problem constants: B=8, C=256, K=64, T=1000
constexpr int Bn  = 8;
constexpr int Cn  = 256;
constexpr int Kn  = 64;
constexpr int Tn  = 1000;
constexpr int TP  = 1024;  // padded T for xbf
constexpr int CH  = 16;    // K1 t-chunk
constexpr int NCH = 64;    // chunks per b

constexpr int XT_P = 264;  // xT[t][c] bf16 pitch (16B-aligned rows)
constexpr int MW_P = 20;   // Mw[k][t] f32 pitch

typedef float f32x4 __attribute__((ext_vector_type(4)));
typedef __bf16 bf16x8 __attribute__((ext_vector_type(8)));

__device__ __forceinline__ unsigned short f2bf(float f) {
    unsigned u = __float_as_uint(f);
    return (unsigned short)((u + 0x7FFFu + ((u >> 16) & 1u)) >> 16);  // RNE
}

union BF8 { unsigned short u[8]; bf16x8 v; };

// ---------------------------------------------------------------------------
// K1 weights: grid (b x 64 chunks of 16t) = 512 blocks, 256 thr (4 waves).
//   Also emits xbf[b][c][t] bf16 (T padded to 1024 with zeros) from the
//   staging registers — K2 then never touches fp32 x (no f2bf in K2).
//   M[k,t] = sum_c codes[c,k]*x[c,t] via mfma; softmax fp32;
//   w_g bf16 (0 for t>=1000); Sp[b,k,ch] per-chunk sums.
// ---------------------------------------------------------------------------
__global__ __launch_bounds__(256) void lde_w(
    const float* __restrict__ x,            // (B, C, T)
    const float* __restrict__ codes,        // (C, K)
    const float* __restrict__ scales,       // (K)
    unsigned short* __restrict__ xbf,       // (B, C, TP) bf16
    unsigned short* __restrict__ w_g,       // (B, NCH, K, CH) bf16
    float* __restrict__ Sp)                 // (B, K, NCH)
{
    __shared__ __align__(16) unsigned short xT[CH * XT_P];  // [t][c] bf16
    __shared__ float Mw[Kn * MW_P];                         // [k][t]
    __shared__ float xsqp[64 * 17];
    __shared__ float xsq4[64];    // [w][t] partials, 4 waves x 16 t
    __shared__ float csqs[Kn];
    __shared__ float spw[4 * 64];

    const int tid  = threadIdx.x;
    const int wave = tid >> 6;
    const int lane = tid & 63;
    const int n    = lane & 15;
    const int q    = lane >> 4;
    const int b    = blockIdx.x >> 6;
    const int ch   = blockIdx.x & 63;
    const int t0   = ch * CH;
    const float* xb = x + (size_t)b * Cn * Tn;

    // --- stage xT (bf16) + xbf global + xsq partials, all from fp32 regs ---
    {
        const int tf = tid & 3;
        float sq0 = 0.f, sq1 = 0.f, sq2 = 0.f, sq3 = 0.f;
#pragma unroll
        for (int r = 0; r < 4; ++r) {
            int c = (tid >> 2) + 64 * r;
            int t = t0 + 4 * tf;
            float4 v;
            if (t + 3 < Tn) {
                v = *(const float4*)(xb + c * Tn + t);
            } else {
                v.x = (t     < Tn) ? xb[c * Tn + t]     : 0.f;
                v.y = (t + 1 < Tn) ? xb[c * Tn + t + 1] : 0.f;
                v.z = (t + 2 < Tn) ? xb[c * Tn + t + 2] : 0.f;
                v.w = (t + 3 < Tn) ? xb[c * Tn + t + 3] : 0.f;
            }
            ushort4 h = make_ushort4(f2bf(v.x), f2bf(v.y), f2bf(v.z), f2bf(v.w));
            xT[(4 * tf + 0) * XT_P + c] = h.x;
            xT[(4 * tf + 1) * XT_P + c] = h.y;
            xT[(4 * tf + 2) * XT_P + c] = h.z;
            xT[(4 * tf + 3) * XT_P + c] = h.w;
            *(ushort4*)(xbf + (((size_t)(b * Cn + c)) << 10) + t0 + 4 * tf) = h;
            sq0 = fmaf(v.x, v.x, sq0);
            sq1 = fmaf(v.y, v.y, sq1);
            sq2 = fmaf(v.z, v.z, sq2);
            sq3 = fmaf(v.w, v.w, sq3);
        }
        float* xp = xsqp + (tid >> 2) * 17 + 4 * tf;
        xp[0] = sq0; xp[1] = sq1; xp[2] = sq2; xp[3] = sq3;
    }
    __syncthreads();

    // xsq reduction spread across all 4 waves
    if (lane < 16) {
        float a = 0.f;
#pragma unroll
        for (int i = 0; i < 16; ++i) a += xsqp[(wave * 16 + i) * 17 + lane];
        xsq4[wave * 16 + lane] = a;
    }

    // --- M GEMM: wave = k-tile. A from global fp32 codes (converted bf16,
    //     csq exact fp32 en route); B from LDS xT. ---
    {
        const int kglob = wave * 16 + n;
        const float* cod = codes + (q * 8) * Kn + kglob;  // codes[c][k]
        float csq_part = 0.f;
        f32x4 acc = {0.f, 0.f, 0.f, 0.f};
#pragma unroll
        for (int c0 = 0; c0 < Cn; c0 += 32) {
            float cf[8];
#pragma unroll
            for (int j = 0; j < 8; ++j) cf[j] = cod[(size_t)(c0 + j) * Kn];
            BF8 aF;
#pragma unroll
            for (int j = 0; j < 8; ++j) {
                csq_part = fmaf(cf[j], cf[j], csq_part);
                aF.u[j] = f2bf(cf[j]);
            }
            bf16x8 bF = *(const bf16x8*)(xT + n * XT_P + c0 + q * 8);
            acc = __builtin_amdgcn_mfma_f32_16x16x32_bf16(aF.v, bF, acc, 0, 0, 0);
        }
        csq_part += __shfl_xor(csq_part, 16, 64);
        csq_part += __shfl_xor(csq_part, 32, 64);
        if (q == 0) csqs[kglob] = csq_part;
#pragma unroll
        for (int r = 0; r < 4; ++r)
            Mw[(wave * 16 + q * 4 + r) * MW_P + n] = acc[r];  // col n -> t
    }
    __syncthreads();

    // --- softmax over k (lane = k); wave handles t = wave*4..+3 ---
    {
        const float sc = scales[lane];
        const float cq = csqs[lane];
        unsigned short wh[4];
        float sp = 0.f;
#pragma unroll
        for (int j = 0; j < 4; ++j) {
            int t = wave * 4 + j;
            float xs_t  = xsq4[t] + xsq4[16 + t] + xsq4[32 + t] + xsq4[48 + t];
            float m     = Mw[lane * MW_P + t];
            float logit = -sc * (xs_t - 2.f * m + cq);
            float mx = logit;
#pragma unroll
            for (int off = 32; off >= 1; off >>= 1)
                mx = fmaxf(mx, __shfl_xor(mx, off, 64));
            float e = __expf(logit - mx);
            float s = e;
#pragma unroll
            for (int off = 32; off >= 1; off >>= 1)
                s += __shfl_xor(s, off, 64);
            float wv = e / s;
            if (t0 + t >= Tn) wv = 0.f;
            sp += wv;
            wh[j] = f2bf(wv);
        }
        *(ushort4*)(w_g + ((size_t)(b * NCH + ch) * Kn + lane) * CH + wave * 4) =
            make_ushort4(wh[0], wh[1], wh[2], wh[3]);
        spw[wave * 64 + lane] = sp;
    }
    __syncthreads();
    if (wave == 0) {
        float s4 = spw[lane] + spw[64 + lane] + spw[128 + lane] + spw[192 + lane];
        Sp[((size_t)b * Kn + lane) * NCH + ch] = s4;
    }
}

// ---------------------------------------------------------------------------
// K2 pool+finish fused: grid (b x kt) = 32 blocks x 512 thr (8 waves).
// Wave w owns c-tiles {w, w+8}; block owns all 256 c for its 16 k, so the
// c-norm is in-block (no third dispatch). All MFMA operands bf16 from ws
// (zero conversion VALU). Epilogue: codes dwordx4 correction, shuffle +
// LDS norm reduce, rsqrt, store.
// ---------------------------------------------------------------------------
__global__ __launch_bounds__(512) void lde_pf(
    const unsigned short* __restrict__ xbf, // (B, C, TP) bf16
    const unsigned short* __restrict__ w_g, // (B, NCH, K, CH) bf16
    const float* __restrict__ Sp,           // (B, K, NCH)
    const float* __restrict__ codes,        // (C, K)
    float* __restrict__ out)                // (B, K, C)
{
    __shared__ float S_l[16];
    __shared__ float normp[8 * 16];
    __shared__ float nscale[16];

    const int tid  = threadIdx.x;
    const int wave = tid >> 6;
    const int lane = tid & 63;
    const int n    = lane & 15;
    const int q    = lane >> 4;
    const int b    = blockIdx.x >> 2;
    const int kt   = blockIdx.x & 3;

    // --- S[k] for this block's 16 k: wave w reduces rows 2w, 2w+1 ---
#pragma unroll
    for (int j = 0; j < 2; ++j) {
        const int kk = wave * 2 + j;
        float s = Sp[((size_t)(b * Kn + kt * 16 + kk)) * NCH + lane];
#pragma unroll
        for (int off = 32; off >= 1; off >>= 1) s += __shfl_xor(s, off, 64);
        if (lane == 0) S_l[kk] = s;
    }

    // --- GEMM: A = w (16k x 32t frag, reused), B = xbf for 2 c-tiles ---
    const int ct0 = wave;              // and ct0 + 8
    const unsigned short* xr0 = xbf + (((size_t)(b * Cn + ct0 * 16 + n)) << 10) + q * 8;
    const unsigned short* xr1 = xr0 + ((size_t)(8 * 16) << 10);
    const unsigned short* wbase =
        w_g + (size_t)b * NCH * Kn * CH + (kt * 16 + n) * CH + (q & 1) * 8;
    const int qh = q >> 1;

    f32x4 a0 = {0.f, 0.f, 0.f, 0.f};
    f32x4 a1 = {0.f, 0.f, 0.f, 0.f};
#pragma unroll 8
    for (int tc = 0; tc < 32; ++tc) {
        bf16x8 aF = *(const bf16x8*)(wbase + (size_t)(2 * tc + qh) * (Kn * CH));
        bf16x8 b0 = *(const bf16x8*)(xr0 + tc * 32);
        bf16x8 b1 = *(const bf16x8*)(xr1 + tc * 32);
        a0 = __builtin_amdgcn_mfma_f32_16x16x32_bf16(aF, b0, a0, 0, 0, 0);
        a1 = __builtin_amdgcn_mfma_f32_16x16x32_bf16(aF, b1, a1, 0, 0, 0);
    }
    __syncthreads();   // S_l ready; all MFMA issued

    // --- epilogue: correction + per-k norm over c ---
    const float invT = 1.0f / (float)Tn;
    f32x4 c0v = *(const f32x4*)(codes + (ct0 * 16 + n) * Kn + kt * 16 + q * 4);
    f32x4 c1v = *(const f32x4*)(codes + ((ct0 + 8) * 16 + n) * Kn + kt * 16 + q * 4);

    float e0[4], e1[4], qq[4];
#pragma unroll
    for (int r = 0; r < 4; ++r) {
        float Sr = S_l[q * 4 + r];
        e0[r] = (a0[r] - c0v[r] * Sr) * invT;
        e1[r] = (a1[r] - c1v[r] * Sr) * invT;
        qq[r] = e0[r] * e0[r] + e1[r] * e1[r];
    }
#pragma unroll
    for (int off = 8; off >= 1; off >>= 1) {
#pragma unroll
        for (int r = 0; r < 4; ++r) qq[r] += __shfl_xor(qq[r], off, 64);
    }
    if (n == 0) {
#pragma unroll
        for (int r = 0; r < 4; ++r) normp[wave * 16 + q * 4 + r] = qq[r];
    }
    __syncthreads();
    if (tid < 16) {
        float t = 0.f;
#pragma unroll
        for (int w = 0; w < 8; ++w) t += normp[w * 16 + tid];
        nscale[tid] = 1.0f / fmaxf(sqrtf(t), 1e-12f);
    }
    __syncthreads();

    float* ob = out + ((size_t)(b * Kn + kt * 16 + q * 4)) * Cn;
#pragma unroll
    for (int r = 0; r < 4; ++r) {
        float ns = nscale[q * 4 + r];
        ob[(size_t)r * Cn + ct0 * 16 + n]       = e0[r] * ns;
        ob[(size_t)r * Cn + (ct0 + 8) * 16 + n] = e1[r] * ns;
    }
}

extern "C" void kernel_launch(void* const* d_in, const int* in_sizes, int n_in,
                              void* d_out, int out_size, void* d_ws, size_t ws_size,
                              hipStream_t stream) {
    const float* x      = (const float*)d_in[0];   // (B, C, T) f32
    const float* codes  = (const float*)d_in[1];   // (C, K)    f32
    const float* scales = (const float*)d_in[2];   // (K)       f32
    float* out = (float*)d_out;                    // (B, K, C) f32

    char* ws = (char*)d_ws;
    unsigned short* xbf = (unsigned short*)ws;                  // 4 MiB
    unsigned short* w_g = (unsigned short*)(ws + (4u << 20));   // 1 MiB
    float*          Sp  = (float*)(ws + (5u << 20));            // 128 KiB

    lde_w <<<Bn * NCH, 256, 0, stream>>>(x, codes, scales, xbf, w_g, Sp);
    lde_pf<<<Bn * 4,   512, 0, stream>>>(xbf, w_g, Sp, codes, out);
}

// Round 12
// 75.906 us; speedup vs baseline: 1.1841x; 1.1841x over previous
//
#include <hip/hip_runtime.h>
#include <stdint.h>

// Problem constants: B=8, C=256, K=64, T=1000
constexpr int Bn  = 8;
constexpr int Cn  = 256;
constexpr int Kn  = 64;
constexpr int Tn  = 1000;
constexpr int CH  = 16;    // K1 t-chunk (T padded to 1024)
constexpr int NCH = 64;    // chunks per b

constexpr int XT_P = 264;  // xT[t][c] bf16 pitch (16B-aligned rows)
constexpr int MW_P = 20;   // Mw[k][t] f32 pitch

typedef float f32x4 __attribute__((ext_vector_type(4)));
typedef __bf16 bf16x8 __attribute__((ext_vector_type(8)));

// Native bf16 convert (v_cvt_pk_bf16_f32 on gfx950, RNE — bit-identical to
// the manual RNE sequence for normal values, 1/3 the VALU).
__device__ __forceinline__ unsigned short hbf(float f) {
    __bf16 h = (__bf16)f;
    return __builtin_bit_cast(unsigned short, h);
}

// ---------------------------------------------------------------------------
// K1 weights: grid (b x 64 chunks of 16t) = 512 blocks, 256 thr (4 waves).
//   M[k,t] = sum_c codes[c,k]*x[c,t] via mfma (A: strided global fp32 codes
//   converted in-register, csq exact fp32 en route; B: LDS xT bf16).
//   w = softmax_k(-scales[k]*(xsq - 2M + csq)) -> w_g bf16 (0 for t>=1000)
//   Sp[b,k,ch] = per-chunk sum_t w.
// ---------------------------------------------------------------------------
__global__ __launch_bounds__(256) void lde_w(
    const float* __restrict__ x,            // (B, C, T)
    const float* __restrict__ codes,        // (C, K)
    const float* __restrict__ scales,       // (K)
    unsigned short* __restrict__ w_g,       // (B, NCH, K, CH) bf16
    float* __restrict__ Sp)                 // (B, K, NCH)
{
    __shared__ __align__(16) unsigned short xT[CH * XT_P];  // [t][c] bf16
    __shared__ float Mw[Kn * MW_P];                         // [k][t]
    __shared__ float xsqp[64 * 17];
    __shared__ float xsq4[64];    // [w][t] partials, 4 waves x 16 t
    __shared__ float csqs[Kn];
    __shared__ float spw[4 * 64];

    const int tid  = threadIdx.x;
    const int wave = tid >> 6;
    const int lane = tid & 63;
    const int n    = lane & 15;
    const int q    = lane >> 4;
    const int b    = blockIdx.x >> 6;
    const int ch   = blockIdx.x & 63;
    const int t0   = ch * CH;
    const float* xb = x + (size_t)b * Cn * Tn;

    // --- stage xT (bf16) + xsq partials from the same fp32 registers ---
    {
        const int tf = tid & 3;
        float sq0 = 0.f, sq1 = 0.f, sq2 = 0.f, sq3 = 0.f;
#pragma unroll
        for (int r = 0; r < 4; ++r) {
            int c = (tid >> 2) + 64 * r;
            int t = t0 + 4 * tf;
            float4 v;
            if (t + 3 < Tn) {
                v = *(const float4*)(xb + c * Tn + t);
            } else {
                v.x = (t     < Tn) ? xb[c * Tn + t]     : 0.f;
                v.y = (t + 1 < Tn) ? xb[c * Tn + t + 1] : 0.f;
                v.z = (t + 2 < Tn) ? xb[c * Tn + t + 2] : 0.f;
                v.w = (t + 3 < Tn) ? xb[c * Tn + t + 3] : 0.f;
            }
            xT[(4 * tf + 0) * XT_P + c] = hbf(v.x);
            xT[(4 * tf + 1) * XT_P + c] = hbf(v.y);
            xT[(4 * tf + 2) * XT_P + c] = hbf(v.z);
            xT[(4 * tf + 3) * XT_P + c] = hbf(v.w);
            sq0 = fmaf(v.x, v.x, sq0);
            sq1 = fmaf(v.y, v.y, sq1);
            sq2 = fmaf(v.z, v.z, sq2);
            sq3 = fmaf(v.w, v.w, sq3);
        }
        float* xp = xsqp + (tid >> 2) * 17 + 4 * tf;
        xp[0] = sq0; xp[1] = sq1; xp[2] = sq2; xp[3] = sq3;
    }
    __syncthreads();

    // xsq reduction spread across all 4 waves (16 rows each)
    if (lane < 16) {
        float a = 0.f;
#pragma unroll
        for (int i = 0; i < 16; ++i) a += xsqp[(wave * 16 + i) * 17 + lane];
        xsq4[wave * 16 + lane] = a;
    }

    // --- M GEMM: wave = k-tile. A from global fp32 codes, converted bf16;
    //     csq[k] exact fp32 along the way. B from LDS xT. ---
    {
        const int kglob = wave * 16 + n;
        const float* cod = codes + (q * 8) * Kn + kglob;  // codes[c][k]
        float csq_part = 0.f;
        f32x4 acc = {0.f, 0.f, 0.f, 0.f};
#pragma unroll
        for (int c0 = 0; c0 < Cn; c0 += 32) {
            float cf[8];
#pragma unroll
            for (int j = 0; j < 8; ++j) cf[j] = cod[(size_t)(c0 + j) * Kn];
            bf16x8 aF;
#pragma unroll
            for (int j = 0; j < 8; ++j) {
                csq_part = fmaf(cf[j], cf[j], csq_part);
                aF[j] = (__bf16)cf[j];
            }
            bf16x8 bF = *(const bf16x8*)(xT + n * XT_P + c0 + q * 8);
            acc = __builtin_amdgcn_mfma_f32_16x16x32_bf16(aF, bF, acc, 0, 0, 0);
        }
        csq_part += __shfl_xor(csq_part, 16, 64);
        csq_part += __shfl_xor(csq_part, 32, 64);
        if (q == 0) csqs[kglob] = csq_part;
#pragma unroll
        for (int r = 0; r < 4; ++r)
            Mw[(wave * 16 + q * 4 + r) * MW_P + n] = acc[r];  // col n -> t
    }
    __syncthreads();

    // --- softmax over k (lane = k); wave handles t = wave*4..+3 ---
    {
        const float sc = scales[lane];
        const float cq = csqs[lane];
        unsigned short wh[4];
        float sp = 0.f;
#pragma unroll
        for (int j = 0; j < 4; ++j) {
            int t = wave * 4 + j;
            float xs_t  = xsq4[t] + xsq4[16 + t] + xsq4[32 + t] + xsq4[48 + t];
            float m     = Mw[lane * MW_P + t];
            float logit = -sc * (xs_t - 2.f * m + cq);
            float mx = logit;
#pragma unroll
            for (int off = 32; off >= 1; off >>= 1)
                mx = fmaxf(mx, __shfl_xor(mx, off, 64));
            float e = __expf(logit - mx);
            float s = e;
#pragma unroll
            for (int off = 32; off >= 1; off >>= 1)
                s += __shfl_xor(s, off, 64);
            float wv = e / s;
            if (t0 + t >= Tn) wv = 0.f;
            sp += wv;
            wh[j] = hbf(wv);
        }
        *(ushort4*)(w_g + ((size_t)(b * NCH + ch) * Kn + lane) * CH + wave * 4) =
            make_ushort4(wh[0], wh[1], wh[2], wh[3]);
        spw[wave * 64 + lane] = sp;
    }
    __syncthreads();
    if (wave == 0) {
        float s4 = spw[lane] + spw[64 + lane] + spw[128 + lane] + spw[192 + lane];
        Sp[((size_t)b * Kn + lane) * NCH + ch] = s4;
    }
}

// ---------------------------------------------------------------------------
// K2 pure GEMM: grid (b x 16 c-tiles x 4 k-tiles) = 512 blocks of ONE wave.
// No LDS, no barriers. Ew[b,k,c] = sum_t w[k,t]*x[c,t] (raw, no correction).
// A-frags contiguous from w_g; B-frags from 2 coalesced float4 x loads per
// step with native bf16 convert. w=0 for t>=1000 makes the tail exact; last
// step guards OOB reads.
// ---------------------------------------------------------------------------
__global__ __launch_bounds__(64) void lde_gemm(
    const float* __restrict__ x,            // (B, C, T)
    const unsigned short* __restrict__ w_g, // (B, NCH, K, CH) bf16
    float* __restrict__ Ew)                 // (B, K, C) raw Xw sums
{
    const int lane = threadIdx.x;
    const int n    = lane & 15;
    const int q    = lane >> 4;
    const int bid  = blockIdx.x;
    const int kt   = bid & 3;
    const int ct   = (bid >> 2) & 15;
    const int b    = bid >> 6;

    const float* xrow = x + (size_t)(b * Cn + ct * 16 + n) * Tn;
    const unsigned short* wbase =
        w_g + (size_t)b * NCH * Kn * CH + (kt * 16 + n) * CH + (q & 1) * 8;
    const int qh = q >> 1;

    f32x4 acc = {0.f, 0.f, 0.f, 0.f};
#pragma unroll 4
    for (int tc = 0; tc < 31; ++tc) {
        bf16x8 aF = *(const bf16x8*)(wbase + (size_t)(2 * tc + qh) * (Kn * CH));
        float4 v0 = *(const float4*)(xrow + tc * 32 + q * 8);
        float4 v1 = *(const float4*)(xrow + tc * 32 + q * 8 + 4);
        bf16x8 bF;
        bF[0] = (__bf16)v0.x; bF[1] = (__bf16)v0.y;
        bF[2] = (__bf16)v0.z; bF[3] = (__bf16)v0.w;
        bF[4] = (__bf16)v1.x; bF[5] = (__bf16)v1.y;
        bF[6] = (__bf16)v1.z; bF[7] = (__bf16)v1.w;
        acc = __builtin_amdgcn_mfma_f32_16x16x32_bf16(aF, bF, acc, 0, 0, 0);
    }
    {   // tc = 31: t = 992..1023, guard t >= 1000 (w is 0 there)
        bf16x8 aF = *(const bf16x8*)(wbase + (size_t)(62 + qh) * (Kn * CH));
        const int tbase = 31 * 32 + q * 8;
        bf16x8 bF;
#pragma unroll
        for (int j = 0; j < 8; ++j) {
            int t = tbase + j;
            bF[j] = (t < Tn) ? (__bf16)xrow[t] : (__bf16)0.f;
        }
        acc = __builtin_amdgcn_mfma_f32_16x16x32_bf16(aF, bF, acc, 0, 0, 0);
    }
    // D: col n -> c, row q*4+r -> k
    float* er = Ew + ((size_t)b * Kn + kt * 16 + q * 4) * Cn + ct * 16 + n;
#pragma unroll
    for (int r = 0; r < 4; ++r)
        er[(size_t)r * Cn] = acc[r];
}

// ---------------------------------------------------------------------------
// K3 finish: block per (b,k), 256 thr = c. Contiguous 1KB Ew row.
//   e = (Ew - codes[c,k]*S)/T ; out = e / max(||e||_c, eps)
// ---------------------------------------------------------------------------
__global__ __launch_bounds__(256) void lde_fin(
    const float* __restrict__ Ew,      // (B, K, C)
    const float* __restrict__ Sp,      // (B, K, NCH)
    const float* __restrict__ codes,   // (C, K)
    float* __restrict__ out)           // (B, K, C)
{
    const int b    = blockIdx.x >> 6;
    const int k    = blockIdx.x & 63;
    const int tid  = threadIdx.x;
    const int lane = tid & 63;
    const int wave = tid >> 6;

    __shared__ float red[4];
    __shared__ float Ss;

    if (wave == 0) {
        float s = Sp[((size_t)b * Kn + k) * NCH + lane];   // 256B coalesced
#pragma unroll
        for (int off = 32; off >= 1; off >>= 1) s += __shfl_xor(s, off, 64);
        if (lane == 0) Ss = s;
    }
    __syncthreads();
    const float S = Ss;

    const int c = tid;
    float val = Ew[((size_t)b * Kn + k) * Cn + c];
    float e = (val - codes[c * Kn + k] * S) * (1.0f / (float)Tn);

    float qq = e * e;
#pragma unroll
    for (int off = 32; off >= 1; off >>= 1) qq += __shfl_xor(qq, off, 64);
    if (lane == 0) red[wave] = qq;
    __syncthreads();
    float nn = sqrtf(red[0] + red[1] + red[2] + red[3]);

    out[((size_t)b * Kn + k) * Cn + c] = e / fmaxf(nn, 1e-12f);
}

extern "C" void kernel_launch(void* const* d_in, const int* in_sizes, int n_in,
                              void* d_out, int out_size, void* d_ws, size_t ws_size,
                              hipStream_t stream) {
    const float* x      = (const float*)d_in[0];   // (B, C, T) f32
    const float* codes  = (const float*)d_in[1];   // (C, K)    f32
    const float* scales = (const float*)d_in[2];   // (K)       f32
    float* out = (float*)d_out;                    // (B, K, C) f32

    char* ws = (char*)d_ws;
    unsigned short* w_g = (unsigned short*)ws;                  // 1 MB
    float*          Sp  = (float*)(ws + (1u << 20));            // 128 KB
    float*          Ew  = (float*)(ws + (1u << 20) + (128u << 10)); // 512 KB

    lde_w   <<<Bn * NCH,     256, 0, stream>>>(x, codes, scales, w_g, Sp);
    lde_gemm<<<Bn * 16 * 4,  64,  0, stream>>>(x, w_g, Ew);
    lde_fin <<<Bn * Kn,      256, 0, stream>>>(Ew, Sp, codes, out);
}